// Round 4
// baseline (29.478 us; speedup 1.0000x reference)
//
#include <hip/hip_runtime.h>
#include <hip/hip_bf16.h>

// x: [N=1024, C=3, T=300, V=25] float32 -> out: [N, T, V] float32
// angle = dot(h,d)/(|h||d|), h = x[:,16]-x[:,12], d = x[:,v]-x[:,16] (d=h at v=16)
// NaN->0, negative->+1. Joint-1 centering cancels algebraically.
//
// Each thread computes 4 groups of 4 consecutive flat outputs (float4),
// groups strided by 256 within the block so every wave access stays
// coalesced. ngroups = 1,920,000 = 1875 * 1024 exactly -> no bounds checks.
// Phase 1 issues all 12 independent 16B data loads; row params follow;
// stores are non-temporal (out is write-once, keep L2/L3 for input).

#define CH_F 7500    // floats per channel per sample (T*V) == out floats per sample
#define N_F 22500    // floats per sample (3 channels)

typedef float f32x4 __attribute__((ext_vector_type(4)));  // native vector: ok for nontemporal builtins

__global__ __launch_bounds__(256) void symmetry_angle_vec4x4(
    const float* __restrict__ x, float* __restrict__ out) {
  const int gbase = blockIdx.x * 1024 + threadIdx.x;

  f32x4 A0[4], A1[4], A2[4];
  int flat_[4], r_[4];
  const float* xb_[4];

  // Phase 1: independent streaming data loads (12 dwordx4 loads in flight)
#pragma unroll
  for (int k = 0; k < 4; ++k) {
    int f = (gbase + (k << 8)) << 2;
    int n = f / CH_F;                 // magic-mul
    int r = f - n * CH_F;             // 0..7496, multiple of 4
    flat_[k] = f;
    r_[k] = r;
    const float* xb = x + n * N_F;
    xb_[k] = xb;
    A0[k] = *(const f32x4*)(xb + r);
    A1[k] = *(const f32x4*)(xb + CH_F + r);
    A2[k] = *(const f32x4*)(xb + 2 * CH_F + r);
  }

  // Phase 2+3: row params + compute + store, per group
#pragma unroll
  for (int k = 0; k < 4; ++k) {
    const float* xb = xb_[k];
    int r = r_[k];
    int t = r / 25;
    int v0 = r - t * 25;
    int ro = t * 25;

    float xa16 = xb[ro + 16];
    float ya16 = xb[CH_F + ro + 16];
    float za16 = xb[2 * CH_F + ro + 16];
    float ha0 = xa16 - xb[ro + 12];
    float ha1 = ya16 - xb[CH_F + ro + 12];
    float ha2 = za16 - xb[2 * CH_F + ro + 12];
    float inva = rsqrtf(ha0 * ha0 + ha1 * ha1 + ha2 * ha2);

    float xbb16 = xa16, ybb16 = ya16, zbb16 = za16;
    float hb0 = ha0, hb1 = ha1, hb2 = ha2, invb = inva;
    if (v0 >= 22) {                    // group straddles into row t+1
      int ro2 = ro + 25;
      xbb16 = xb[ro2 + 16];
      ybb16 = xb[CH_F + ro2 + 16];
      zbb16 = xb[2 * CH_F + ro2 + 16];
      hb0 = xbb16 - xb[ro2 + 12];
      hb1 = ybb16 - xb[CH_F + ro2 + 12];
      hb2 = zbb16 - xb[2 * CH_F + ro2 + 12];
      invb = rsqrtf(hb0 * hb0 + hb1 * hb1 + hb2 * hb2);
    }

    float e0[4] = {A0[k].x, A0[k].y, A0[k].z, A0[k].w};
    float e1[4] = {A1[k].x, A1[k].y, A1[k].z, A1[k].w};
    float e2[4] = {A2[k].x, A2[k].y, A2[k].z, A2[k].w};
    float res[4];
#pragma unroll
    for (int e = 0; e < 4; ++e) {
      int ve = v0 + e;
      bool second = ve >= 25;
      float X16 = second ? xbb16 : xa16;
      float Y16 = second ? ybb16 : ya16;
      float Z16 = second ? zbb16 : za16;
      float H0 = second ? hb0 : ha0;
      float H1 = second ? hb1 : ha1;
      float H2 = second ? hb2 : ha2;
      float INV = second ? invb : inva;
      int vv = second ? ve - 25 : ve;
      float d0, d1, d2;
      if (vv == 16) { d0 = H0; d1 = H1; d2 = H2; }
      else { d0 = e0[e] - X16; d1 = e1[e] - Y16; d2 = e2[e] - Z16; }
      float nd  = d0 * d0 + d1 * d1 + d2 * d2;
      float dot = H0 * d0 + H1 * d1 + H2 * d2;
      float ang = dot * INV * rsqrtf(nd);
      if (ang != ang) ang = 0.0f;      // nan_to_num
      if (ang < 0.0f) ang += 1.0f;     // where(angle<0, angle+1, angle)
      res[e] = ang;
    }
    f32x4 o = {res[0], res[1], res[2], res[3]};
    __builtin_nontemporal_store(o, (f32x4*)(out + flat_[k]));
  }
}

extern "C" void kernel_launch(void* const* d_in, const int* in_sizes, int n_in,
                              void* d_out, int out_size, void* d_ws, size_t ws_size,
                              hipStream_t stream) {
  const float* x = (const float*)d_in[0];
  float* out = (float*)d_out;
  // out_size = 7,680,000 floats -> 1,920,000 groups -> 1875 blocks x 256 thr x 4 groups
  int grid = (out_size >> 2) / 1024;
  symmetry_angle_vec4x4<<<grid, 256, 0, stream>>>(x, out);
}

// Round 5
// 26.717 us; speedup vs baseline: 1.1033x; 1.1033x over previous
//
#include <hip/hip_runtime.h>
#include <hip/hip_bf16.h>

// x: [N=1024, C=3, T=300, V=25] float32 -> out: [N, T, V] float32
// angle = dot(h,d)/(|h||d|), h = x[:,16]-x[:,12], d = x[:,v]-x[:,16] (d=h at v=16)
// NaN->0, negative->+1. Joint-1 centering cancels algebraically.
//
// One thread = 8 CONSECUTIVE flat outputs (2 adjacent float4 groups), so the
// row-param work (x16/x12 loads, hip vector, rsqrt) amortizes over 8 outputs;
// 8 consecutive elements span at most 2 joint-rows (V=25), same as 4 did.
// 7500 % 8 != 0 -> per-sample decomposition: 937 full threads + 1 tail thread
// handling the last 4 floats. 1024*938 = 960,512 threads = 3752 blocks x 256.

#define CH_F 7500    // floats per channel per sample (T*V) == out floats per sample
#define N_F 22500    // floats per sample (3 channels)

typedef float f32x4 __attribute__((ext_vector_type(4)));

__global__ __launch_bounds__(256) void symmetry_angle_row8(
    const float* __restrict__ x, float* __restrict__ out) {
  int tid = blockIdx.x * 256 + threadIdx.x;
  int n = tid / 938;                 // magic-mul
  int j = tid - n * 938;             // 0..937 within sample
  bool tail = (j == 937);            // last 4 floats of the sample
  int r = j * 8;                     // 0..7496, multiple of 8 (tail: 7496)
  const float* xb = x + n * N_F;
  int flat = n * CH_F + r;

  // Data loads: 8 consecutive floats per channel (2 x dwordx4); tail loads 4.
  f32x4 a0 = *(const f32x4*)(xb + r);
  f32x4 a1 = *(const f32x4*)(xb + CH_F + r);
  f32x4 a2 = *(const f32x4*)(xb + 2 * CH_F + r);
  f32x4 b0 = {0.f, 0.f, 0.f, 0.f}, b1 = b0, b2 = b0;
  if (!tail) {
    b0 = *(const f32x4*)(xb + r + 4);
    b1 = *(const f32x4*)(xb + CH_F + r + 4);
    b2 = *(const f32x4*)(xb + 2 * CH_F + r + 4);
  }

  int t = r / 25;
  int v0 = r - t * 25;
  int ro = t * 25;

  // Row A params (row t)
  float xa16 = xb[ro + 16];
  float ya16 = xb[CH_F + ro + 16];
  float za16 = xb[2 * CH_F + ro + 16];
  float ha0 = xa16 - xb[ro + 12];
  float ha1 = ya16 - xb[CH_F + ro + 12];
  float ha2 = za16 - xb[2 * CH_F + ro + 12];
  float inva = rsqrtf(ha0 * ha0 + ha1 * ha1 + ha2 * ha2);

  // Row B params (row t+1) when the 8-span straddles (v0 >= 18; never on tail)
  float xbb16 = xa16, ybb16 = ya16, zbb16 = za16;
  float hb0 = ha0, hb1 = ha1, hb2 = ha2, invb = inva;
  if (v0 >= 18 && !tail) {
    int ro2 = ro + 25;
    xbb16 = xb[ro2 + 16];
    ybb16 = xb[CH_F + ro2 + 16];
    zbb16 = xb[2 * CH_F + ro2 + 16];
    hb0 = xbb16 - xb[ro2 + 12];
    hb1 = ybb16 - xb[CH_F + ro2 + 12];
    hb2 = zbb16 - xb[2 * CH_F + ro2 + 12];
    invb = rsqrtf(hb0 * hb0 + hb1 * hb1 + hb2 * hb2);
  }

  float e0[8] = {a0.x, a0.y, a0.z, a0.w, b0.x, b0.y, b0.z, b0.w};
  float e1[8] = {a1.x, a1.y, a1.z, a1.w, b1.x, b1.y, b1.z, b1.w};
  float e2[8] = {a2.x, a2.y, a2.z, a2.w, b2.x, b2.y, b2.z, b2.w};
  float res[8];
#pragma unroll
  for (int e = 0; e < 8; ++e) {
    int ve = v0 + e;
    bool second = ve >= 25;
    float X16 = second ? xbb16 : xa16;
    float Y16 = second ? ybb16 : ya16;
    float Z16 = second ? zbb16 : za16;
    float H0 = second ? hb0 : ha0;
    float H1 = second ? hb1 : ha1;
    float H2 = second ? hb2 : ha2;
    float INV = second ? invb : inva;
    int vv = second ? ve - 25 : ve;
    float d0, d1, d2;
    if (vv == 16) { d0 = H0; d1 = H1; d2 = H2; }
    else { d0 = e0[e] - X16; d1 = e1[e] - Y16; d2 = e2[e] - Z16; }
    float nd  = d0 * d0 + d1 * d1 + d2 * d2;
    float dot = H0 * d0 + H1 * d1 + H2 * d2;
    float ang = dot * INV * rsqrtf(nd);
    if (ang != ang) ang = 0.0f;      // nan_to_num
    if (ang < 0.0f) ang += 1.0f;     // where(angle<0, angle+1, angle)
    res[e] = ang;
  }

  f32x4 oA = {res[0], res[1], res[2], res[3]};
  *(f32x4*)(out + flat) = oA;
  if (!tail) {
    f32x4 oB = {res[4], res[5], res[6], res[7]};
    *(f32x4*)(out + flat + 4) = oB;
  }
}

extern "C" void kernel_launch(void* const* d_in, const int* in_sizes, int n_in,
                              void* d_out, int out_size, void* d_ws, size_t ws_size,
                              hipStream_t stream) {
  const float* x = (const float*)d_in[0];
  float* out = (float*)d_out;
  (void)out_size;
  // 1024 samples * 938 threads = 960,512 threads = 3752 blocks of 256 exactly
  int grid = 3752;
  symmetry_angle_row8<<<grid, 256, 0, stream>>>(x, out);
}

// Round 6
// 24.023 us; speedup vs baseline: 1.2271x; 1.1122x over previous
//
#include <hip/hip_runtime.h>
#include <hip/hip_bf16.h>

// x: [N=1024, C=3, T=300, V=25] float32 -> out: [N, T, V] float32
// angle = dot(h,d)/(|h||d|), h = x[:,16]-x[:,12], d = x[:,v]-x[:,16] (d=h at v=16)
// NaN->0, negative->+1. Joint-1 centering cancels algebraically.
//
// Round-2 shape (1 float4 group/thread, 30K waves — best TLP) + block-
// cooperative param staging: a block covers 1024 consecutive floats =
// <=43 joint-rows. Lanes 0..42 (wave 0) each compute one row's params
// (x16[3], h[3], 1/|h|) into LDS; after one barrier every thread reads its
// two candidate rows via 4x ds_read_b128. Eliminates ~12 divergent scalar
// loads per wave and the straddle branch. Data loads issued pre-barrier to
// overlap staging latency.

#define CH_F 7500    // floats per channel per sample (T*V) == out floats per sample
#define N_F 22500    // floats per sample (3 channels)
#define LAST_ROW 307199  // N*T - 1

typedef float f32x4 __attribute__((ext_vector_type(4)));

__global__ __launch_bounds__(256) void symmetry_angle_ldsprm(
    const float* __restrict__ x, float* __restrict__ out) {
  __shared__ float prm[43][8];   // x16_0,x16_1,x16_2,h0 | h1,h2,inv,pad

  const int B  = blockIdx.x * 1024;   // first flat float of this block
  const int R0 = B / 25;              // first global joint-row (n*300+t)
  const int lane = threadIdx.x;

  // ---- main-phase data loads issued first (independent of LDS) ----
  const int flat = B + (lane << 2);
  const int n = flat / CH_F;          // magic-mul
  const int r = flat - n * CH_F;      // multiple of 4; group never crosses n
  const float* xb = x + n * N_F;
  f32x4 a0 = *(const f32x4*)(xb + r);
  f32x4 a1 = *(const f32x4*)(xb + CH_F + r);
  f32x4 a2 = *(const f32x4*)(xb + 2 * CH_F + r);

  // ---- cooperative param staging: one row per lane (wave 0 only) ----
  if (lane < 43) {
    int rt = R0 + lane;
    if (rt > LAST_ROW) rt = LAST_ROW;     // clamp (clamped slots never read)
    int nn = rt / 300;
    int base = rt * 25 + nn * 15000;      // = nn*22500 + t*25
    float x12_0 = x[base + 12];
    float x16_0 = x[base + 16];
    float x12_1 = x[base + CH_F + 12];
    float x16_1 = x[base + CH_F + 16];
    float x12_2 = x[base + 2 * CH_F + 12];
    float x16_2 = x[base + 2 * CH_F + 16];
    float h0 = x16_0 - x12_0;
    float h1 = x16_1 - x12_1;
    float h2 = x16_2 - x12_2;
    float inv = rsqrtf(h0 * h0 + h1 * h1 + h2 * h2);
    prm[lane][0] = x16_0; prm[lane][1] = x16_1;
    prm[lane][2] = x16_2; prm[lane][3] = h0;
    prm[lane][4] = h1;    prm[lane][5] = h2;
    prm[lane][6] = inv;   prm[lane][7] = 0.0f;
  }
  __syncthreads();

  // ---- fetch params for row of elem 0 and row+1 (unconditional) ----
  const int rt = flat / 25;           // global row of first element
  const int v0 = flat - rt * 25;      // 0..24
  const int lr = rt - R0;             // 0..41  (lr+1 <= 42 always staged)
  f32x4 pa0 = *(const f32x4*)&prm[lr][0];
  f32x4 pa1 = *(const f32x4*)&prm[lr][4];
  f32x4 pb0 = *(const f32x4*)&prm[lr + 1][0];
  f32x4 pb1 = *(const f32x4*)&prm[lr + 1][4];

  float e0[4] = {a0.x, a0.y, a0.z, a0.w};
  float e1[4] = {a1.x, a1.y, a1.z, a1.w};
  float e2[4] = {a2.x, a2.y, a2.z, a2.w};
  float res[4];
#pragma unroll
  for (int e = 0; e < 4; ++e) {
    int ve = v0 + e;
    bool second = ve >= 25;
    float X16 = second ? pb0.x : pa0.x;
    float Y16 = second ? pb0.y : pa0.y;
    float Z16 = second ? pb0.z : pa0.z;
    float H0  = second ? pb0.w : pa0.w;
    float H1  = second ? pb1.x : pa1.x;
    float H2  = second ? pb1.y : pa1.y;
    float INV = second ? pb1.z : pa1.z;
    int vv = second ? ve - 25 : ve;
    float d0, d1, d2;
    if (vv == 16) { d0 = H0; d1 = H1; d2 = H2; }
    else { d0 = e0[e] - X16; d1 = e1[e] - Y16; d2 = e2[e] - Z16; }
    float nd  = d0 * d0 + d1 * d1 + d2 * d2;
    float dot = H0 * d0 + H1 * d1 + H2 * d2;
    float ang = dot * INV * rsqrtf(nd);
    if (ang != ang) ang = 0.0f;      // nan_to_num
    if (ang < 0.0f) ang += 1.0f;     // where(angle<0, angle+1, angle)
    res[e] = ang;
  }
  f32x4 o = {res[0], res[1], res[2], res[3]};
  *(f32x4*)(out + flat) = o;
}

extern "C" void kernel_launch(void* const* d_in, const int* in_sizes, int n_in,
                              void* d_out, int out_size, void* d_ws, size_t ws_size,
                              hipStream_t stream) {
  const float* x = (const float*)d_in[0];
  float* out = (float*)d_out;
  // out_size = 7,680,000 floats -> 7500 blocks x 256 threads x 4 floats
  int grid = out_size >> 10;
  symmetry_angle_ldsprm<<<grid, 256, 0, stream>>>(x, out);
}